// Round 1
// baseline (298.883 us; speedup 1.0000x reference)
//
#include <hip/hip_runtime.h>
#include <hip/hip_bf16.h>
#include <stdint.h>

// ---------------------------------------------------------------------------
// SparseLinear: y[B,N] = x[B,M] @ W^T + bias, W given as CSR.
// R5: port the GEMM to the 256^2 8-phase counted-vmcnt schedule (T3+T4+T2+T5).
//   - 256x256 tile, BK=64, 8 waves (2Mx4N), 512 threads, 128 KiB LDS.
//   - 8 phases / 2 K-tiles; buffers are FIXED __shared__ arrays per phase so
//     alias analysis can separate ds_read buffer from global_load_lds target.
//   - per phase: 12 ds_read_b128 || stage 1 half-tile (2x global_load_lds w16)
//     -> s_waitcnt vmcnt(4) (never 0 in main loop) -> raw s_barrier ->
//     setprio(1) + 16 MFMA + setprio(0) -> raw s_barrier.
//   - hazard ledger: stage at phase S first read at >= S+3; vmcnt(4)+barrier
//     at phase P proves stages <= P-2 landed for ALL waves => safe.
//     Quadrant order (0,0),(1,0),(1,1),(0,1); stage order A0,B0,A1,B1 gives
//     gaps 4,3,3,3. WAR: overwrite happens >= 1 barrier after last reader.
//   - LDS XOR swizzle chunk' = chunk ^ (row&7) on 128B rows: ds_read_b128 is
//     2-way (free). global_load_lds keeps a LINEAR dest; the inverse swizzle
//     is applied to the per-lane GLOBAL source address (rule 21).
// Prologues (densify_w, cvt_x_bf16) unchanged from R4 (verified).
// ---------------------------------------------------------------------------

#define B_DIM 4096
#define M_DIM 4096
#define N_DIM 4096
#define NNZ_ROW 819

typedef __attribute__((ext_vector_type(8))) __bf16 bf16x8;
typedef __attribute__((ext_vector_type(4))) float f32x4;

__device__ __forceinline__ unsigned short f32_to_bf16(float f) {
    union { float f; unsigned int u; } v;
    v.f = f;
    unsigned int r = v.u + 0x7FFFu + ((v.u >> 16) & 1u);  // RNE
    return (unsigned short)(r >> 16);
}

__device__ __forceinline__ void load_lds16(const void* g, void* l) {
    __builtin_amdgcn_global_load_lds(
        (const __attribute__((address_space(1))) void*)g,
        (__attribute__((address_space(3))) void*)l,
        16, 0, 0);
}

// ---- prologue 1: densify one W row per block (verified R2) ----------------
__global__ __launch_bounds__(256) void densify_w(
    const float* __restrict__ wval,
    const int* __restrict__ cols,
    unsigned short* __restrict__ wb) {
    __shared__ __attribute__((aligned(16))) unsigned short row_s[M_DIM];  // 8 KB
    const int row = blockIdx.x;
    const int tid = threadIdx.x;
    uint4* rs4 = (uint4*)row_s;
    rs4[tid]       = make_uint4(0u, 0u, 0u, 0u);
    rs4[tid + 256] = make_uint4(0u, 0u, 0u, 0u);
    __syncthreads();
    const size_t base = (size_t)row * NNZ_ROW;
    for (int j = tid; j < NNZ_ROW; j += 256) {
        const int c = cols[base + j];
        row_s[c] = f32_to_bf16(wval[base + j]);
    }
    __syncthreads();
    uint4* dst = (uint4*)(wb + (size_t)row * M_DIM);
    dst[tid]       = rs4[tid];
    dst[tid + 256] = rs4[tid + 256];
}

// ---- prologue 2: X fp32 -> bf16 -------------------------------------------
__global__ __launch_bounds__(256) void cvt_x_bf16(
    const float4* __restrict__ x, uint4* __restrict__ y, int n8) {
    int i = blockIdx.x * 256 + threadIdx.x;
    if (i >= n8) return;
    const float4 a = x[2 * i];
    const float4 b = x[2 * i + 1];
    union { ushort ush[8]; uint4 u4; } o;
    o.ush[0] = f32_to_bf16(a.x); o.ush[1] = f32_to_bf16(a.y);
    o.ush[2] = f32_to_bf16(a.z); o.ush[3] = f32_to_bf16(a.w);
    o.ush[4] = f32_to_bf16(b.x); o.ush[5] = f32_to_bf16(b.y);
    o.ush[6] = f32_to_bf16(b.z); o.ush[7] = f32_to_bf16(b.w);
    y[i] = o.u4;
}

// ---------------------------------------------------------------------------
// Stage one 128-row half-tile (128 rows x 64 k, bf16) for K-offset kt.
// LDS dest is LINEAR: wave w covers segments {2w, 2w+1}; each instruction
// writes 1024B = 8 rows at (uniform base + lane*16). The lane's 16B slot is
// (row r = seg*8 + (l>>3), chunk' = l&7); we want LDS(r, c') to hold global
// chunk c' ^ (r&7), and (r&7)==(l>>3), so src chunk = (l&7) ^ (l>>3).
// ---------------------------------------------------------------------------
__device__ __forceinline__ void stage_half(
    const unsigned short* __restrict__ src,  // global [4096][4096] bf16 bits
    int grow0,                               // global row of half's row 0
    int kt,                                  // k element offset of this K-tile
    unsigned short* dst,                     // LDS half base (ushort*)
    int w, int l) {
#pragma unroll
    for (int j = 0; j < 2; ++j) {
        const int seg = w * 2 + j;                // 0..15
        const int r   = seg * 8 + (l >> 3);       // local row 0..127
        const int cg  = (l >> 3) ^ (l & 7);       // inverse-swizzled src chunk
        load_lds16(src + (size_t)(grow0 + r) * M_DIM + kt + cg * 8,
                   dst + seg * 512);              // 512 ush = 1024 B
    }
}

// ---------------------------------------------------------------------------
// One phase: compute block-level C-quadrant (MA,NB) of the current K-tile
// (waves tile the 128x128 quadrant as 2x4 of 64x32), stage one half-tile of
// the NEXT K-tile (SK: 0=A0,1=B0,2=A1,3=B1).
// Fragment read: row ra = quad + l15 (+16*mf), chunk c = ks*4 + (l>>4),
// stored at chunk' = c ^ (ra&7) = c ^ (l&7). 2-way bank access (free).
// ---------------------------------------------------------------------------
template <int MA, int NB, int SK>
__device__ __forceinline__ void phase_op(
    const unsigned short* As_c, const unsigned short* Bs_c,
    unsigned short* As_n, unsigned short* Bs_n,
    const unsigned short* __restrict__ Xb, const unsigned short* __restrict__ Wb,
    int bm0, int bn0, int kn, bool do_stage,
    int wr, int wc, int w, int l, f32x4 (&acc)[2][4][2][2]) {
    const int l15 = l & 15;
    const int lg  = l >> 4;
    const int lx  = l & 7;
    const int ck0 = (lg ^ lx) << 3;          // ushort offset, k-chunk ks=0
    const int ck1 = ((4 + lg) ^ lx) << 3;    // k-chunk ks=1

    const unsigned short* Ab = As_c + (MA * 128 + wr * 64 + l15) * 64;
    const unsigned short* Bb = Bs_c + (NB * 128 + wc * 32 + l15) * 64;

    bf16x8 af[4][2], bfr[2][2];
#pragma unroll
    for (int mf = 0; mf < 4; ++mf) {
        af[mf][0] = *(const bf16x8*)(Ab + mf * 1024 + ck0);
        af[mf][1] = *(const bf16x8*)(Ab + mf * 1024 + ck1);
    }
#pragma unroll
    for (int nf = 0; nf < 2; ++nf) {
        bfr[nf][0] = *(const bf16x8*)(Bb + nf * 1024 + ck0);
        bfr[nf][1] = *(const bf16x8*)(Bb + nf * 1024 + ck1);
    }

    if (do_stage) {
        if constexpr (SK == 0) stage_half(Xb, bm0,       kn, As_n,        w, l);
        if constexpr (SK == 1) stage_half(Wb, bn0,       kn, Bs_n,        w, l);
        if constexpr (SK == 2) stage_half(Xb, bm0 + 128, kn, As_n + 8192, w, l);
        if constexpr (SK == 3) stage_half(Wb, bn0 + 128, kn, Bs_n + 8192, w, l);
    }

    // Counted wait: all but the newest 2 phase-stages (4 loads) have landed.
    // Never vmcnt(0) in the main loop.
    asm volatile("s_waitcnt vmcnt(4)" ::: "memory");
    asm volatile("s_barrier" ::: "memory");

    __builtin_amdgcn_s_setprio(1);
#pragma unroll
    for (int mf = 0; mf < 4; ++mf)
#pragma unroll
        for (int nf = 0; nf < 2; ++nf) {
            acc[MA][mf][NB][nf] = __builtin_amdgcn_mfma_f32_16x16x32_bf16(
                af[mf][0], bfr[nf][0], acc[MA][mf][NB][nf], 0, 0, 0);
            acc[MA][mf][NB][nf] = __builtin_amdgcn_mfma_f32_16x16x32_bf16(
                af[mf][1], bfr[nf][1], acc[MA][mf][NB][nf], 0, 0, 0);
        }
    __builtin_amdgcn_s_setprio(0);
    asm volatile("s_barrier" ::: "memory");
}

// ---- main GEMM: C[b,n] = sum_k Xb[b,k]*Wb[n,k] + bias[n] -------------------
__global__ __launch_bounds__(512, 2) void gemm_bt_bias(
    const unsigned short* __restrict__ Xb,   // [B][M] bf16 bits
    const unsigned short* __restrict__ Wb,   // [N][M] bf16 bits
    const float* __restrict__ bias,          // [N]
    float* __restrict__ out)                 // [B][N]
{
    // 4 fixed buffers: A/B x double-buffer. 4 x 32 KB = 128 KB LDS.
    __shared__ __attribute__((aligned(16))) unsigned short As0[16384];
    __shared__ __attribute__((aligned(16))) unsigned short Bs0[16384];
    __shared__ __attribute__((aligned(16))) unsigned short As1[16384];
    __shared__ __attribute__((aligned(16))) unsigned short Bs1[16384];

    const int tid = threadIdx.x;
    const int w   = tid >> 6;     // wave 0..7
    const int l   = tid & 63;
    const int wr  = w >> 2;       // 0..1  (64-row slice within quadrant)
    const int wc  = w & 3;        // 0..3  (32-col slice within quadrant)

    // bijective XCD swizzle (256 blocks, 8 XCDs, 32 contiguous per XCD)
    const int wg  = blockIdx.y * 16 + blockIdx.x;
    const int idx = ((wg & 7) << 5) | (wg >> 3);
    const int bm0 = (idx >> 4) * 256;   // batch rows
    const int bn0 = (idx & 15) * 256;   // N cols

    f32x4 acc[2][4][2][2];
#pragma unroll
    for (int a = 0; a < 2; ++a)
#pragma unroll
        for (int b = 0; b < 4; ++b)
#pragma unroll
            for (int c = 0; c < 2; ++c)
#pragma unroll
                for (int d = 0; d < 2; ++d) acc[a][b][c][d] = (f32x4)0.0f;

    // ---- prologue: stage K-tile 0 fully into buf0, drain, barrier ----
    stage_half(Xb, bm0,       0, As0,        w, l);
    stage_half(Wb, bn0,       0, Bs0,        w, l);
    stage_half(Xb, bm0 + 128, 0, As0 + 8192, w, l);
    stage_half(Wb, bn0 + 128, 0, Bs0 + 8192, w, l);
    asm volatile("s_waitcnt vmcnt(0)" ::: "memory");
    asm volatile("s_barrier" ::: "memory");

    // ---- main loop: 2 K-tiles (8 phases) per iteration ----
#pragma unroll 1
    for (int kt = 0; kt < M_DIM; kt += 128) {
        const int k1 = kt + 64;    // tile staged during phases 1-4 (always valid)
        const int k2 = kt + 128;   // tile staged during phases 5-8
        const bool s2 = (k2 < M_DIM);
        phase_op<0,0,0>(As0,Bs0, As1,Bs1, Xb,Wb, bm0,bn0, k1, true, wr,wc,w,l, acc);
        phase_op<1,0,1>(As0,Bs0, As1,Bs1, Xb,Wb, bm0,bn0, k1, true, wr,wc,w,l, acc);
        phase_op<1,1,2>(As0,Bs0, As1,Bs1, Xb,Wb, bm0,bn0, k1, true, wr,wc,w,l, acc);
        phase_op<0,1,3>(As0,Bs0, As1,Bs1, Xb,Wb, bm0,bn0, k1, true, wr,wc,w,l, acc);
        phase_op<0,0,0>(As1,Bs1, As0,Bs0, Xb,Wb, bm0,bn0, k2, s2,   wr,wc,w,l, acc);
        phase_op<1,0,1>(As1,Bs1, As0,Bs0, Xb,Wb, bm0,bn0, k2, s2,   wr,wc,w,l, acc);
        phase_op<1,1,2>(As1,Bs1, As0,Bs0, Xb,Wb, bm0,bn0, k2, s2,   wr,wc,w,l, acc);
        phase_op<0,1,3>(As1,Bs1, As0,Bs0, Xb,Wb, bm0,bn0, k2, s2,   wr,wc,w,l, acc);
    }

    // ---- epilogue: D elem r of acc -> row = (l>>4)*4+r, col = l&15 ----
    const int l15 = l & 15;
    const int lg  = l >> 4;
#pragma unroll
    for (int nb = 0; nb < 2; ++nb)
#pragma unroll
        for (int nf = 0; nf < 2; ++nf) {
            const int col = bn0 + nb * 128 + wc * 32 + nf * 16 + l15;
            const float bv = bias[col];
#pragma unroll
            for (int ma = 0; ma < 2; ++ma)
#pragma unroll
                for (int mf = 0; mf < 4; ++mf) {
                    const int row0 = bm0 + ma * 128 + wr * 64 + mf * 16 + lg * 4;
#pragma unroll
                    for (int r = 0; r < 4; ++r)
                        out[(size_t)(row0 + r) * N_DIM + col] =
                            acc[ma][mf][nb][nf][r] + bv;
                }
        }
}

// ---------------------------------------------------------------------------

extern "C" void kernel_launch(void* const* d_in, const int* in_sizes, int n_in,
                              void* d_out, int out_size, void* d_ws, size_t ws_size,
                              hipStream_t stream) {
    const float* x       = (const float*)d_in[0];
    const float* wval    = (const float*)d_in[1];
    const float* bias    = (const float*)d_in[2];
    const int*   cols    = (const int*)d_in[4];
    float* out = (float*)d_out;

    // workspace: Wb [N*M bf16] (32 MiB) | Xb [B*M bf16] (32 MiB)
    unsigned short* Wb = (unsigned short*)d_ws;
    unsigned short* Xb = Wb + (size_t)N_DIM * M_DIM;

    densify_w<<<dim3(N_DIM), dim3(256), 0, stream>>>(wval, cols, Wb);
    {
        int n8 = (B_DIM * M_DIM) / 8;
        cvt_x_bf16<<<dim3(n8 / 256), dim3(256), 0, stream>>>(
            (const float4*)x, (uint4*)Xb, n8);
    }
    gemm_bt_bias<<<dim3(N_DIM / 256, B_DIM / 256), dim3(512), 0, stream>>>(
        Xb, Wb, bias, out);
}